// Round 1
// baseline (472.215 us; speedup 1.0000x reference)
//
#include <hip/hip_runtime.h>
#include <hip/hip_fp16.h>
#include <stdint.h>

#define V_N   50257
#define NFRQ  256
#define NCH   1024
#define MT    4096      // B*S
#define KC    512       // 2*N_FREQ
#define TWO_PI 6.28318530717958647692f

typedef _Float16 f16;
typedef __attribute__((ext_vector_type(8))) _Float16 f16x8;
typedef __attribute__((ext_vector_type(4))) float    f32x4;

// async global->LDS, 16B per lane; LDS dest = wave-uniform base + lane*16
__device__ __forceinline__ void gload_lds16(const void* g, const void* l) {
  typedef const __attribute__((address_space(1))) unsigned int* gp_t;
  typedef __attribute__((address_space(3))) unsigned int* lp_t;
  __builtin_amdgcn_global_load_lds((gp_t)(uint64_t)(uintptr_t)g,
                                   (lp_t)(uint32_t)(uintptr_t)l, 16, 0, 0);
}

// ---------------- Kernel 1: A[m][2f+e] = (e? Yi : Yr)[m][f],  Y = h @ w -------------
// fp32 inputs reg-staged -> f16 LDS tiles (XOR chunk swizzle) -> 16x16x32 f16 MFMA.
// grid (KC/64, MT/64), 256 thr (4 waves, 2x2 over 64x64 tile, 32x32 per wave).
__global__ __launch_bounds__(256) void k1_proj(
    const float* __restrict__ h, const float* __restrict__ w, f16* __restrict__ A) {
  __shared__ __align__(16) f16 As[64 * 64];
  __shared__ __align__(16) f16 Bs[64 * 64];
  const int tid = threadIdx.x;
  const int bn0 = blockIdx.x * 64;
  const int bm0 = blockIdx.y * 64;
  const int lane = tid & 63, wid = tid >> 6;
  const int lr = lane & 15, lg = lane >> 4;
  const int wr = wid >> 1, wc = wid & 1;

  f32x4 acc[2][2];
#pragma unroll
  for (int i = 0; i < 2; ++i)
#pragma unroll
    for (int j = 0; j < 2; ++j) acc[i][j] = (f32x4){0.f, 0.f, 0.f, 0.f};

  for (int s = 0; s < NCH / 64; ++s) {
    const int k0 = s * 64;
    __syncthreads();
    // stage A tile (h): chunk q -> row m=q>>3, chunk c=q&7 (8 f32 -> 8 f16)
#pragma unroll
    for (int r = 0; r < 2; ++r) {
      int q = tid + r * 256;
      int m = q >> 3, c = q & 7;
      const float* src = h + (size_t)(bm0 + m) * NCH + k0 + c * 8;
      f32x4 v0 = *(const f32x4*)src;
      f32x4 v1 = *(const f32x4*)(src + 4);
      f16x8 pk;
#pragma unroll
      for (int e = 0; e < 4; ++e) { pk[e] = (f16)v0[e]; pk[4 + e] = (f16)v1[e]; }
      *(f16x8*)&As[m * 64 + ((c ^ (m & 7)) << 3)] = pk;
    }
    // stage B tile (w, column-permuted to interleaved layout): Bs[n][k]
#pragma unroll
    for (int r = 0; r < 2; ++r) {
      int q = tid + r * 256;
      int c = q >> 6, n = q & 63;
      int jj = bn0 + n;
      int wcol = (jj >> 1) + ((jj & 1) ? NFRQ : 0);
      f16x8 pk;
#pragma unroll
      for (int j = 0; j < 8; ++j)
        pk[j] = (f16)w[(size_t)(k0 + c * 8 + j) * KC + wcol];
      *(f16x8*)&Bs[n * 64 + ((c ^ (n & 7)) << 3)] = pk;
    }
    __syncthreads();
#pragma unroll
    for (int kk = 0; kk < 2; ++kk) {
      const int cb = kk * 4 + lg;
      f16x8 a[2], b[2];
#pragma unroll
      for (int mi = 0; mi < 2; ++mi) {
        int row = wr * 32 + mi * 16 + lr;
        a[mi] = *(const f16x8*)&As[row * 64 + ((cb ^ (row & 7)) << 3)];
      }
#pragma unroll
      for (int ni = 0; ni < 2; ++ni) {
        int col = wc * 32 + ni * 16 + lr;
        b[ni] = *(const f16x8*)&Bs[col * 64 + ((cb ^ (col & 7)) << 3)];
      }
#pragma unroll
      for (int mi = 0; mi < 2; ++mi)
#pragma unroll
        for (int ni = 0; ni < 2; ++ni)
          acc[mi][ni] = __builtin_amdgcn_mfma_f32_16x16x32_f16(a[mi], b[ni], acc[mi][ni], 0, 0, 0);
    }
  }
#pragma unroll
  for (int mi = 0; mi < 2; ++mi)
#pragma unroll
    for (int ni = 0; ni < 2; ++ni)
#pragma unroll
      for (int r = 0; r < 4; ++r) {
        int row = bm0 + wr * 32 + mi * 16 + lg * 4 + r;
        int col = bn0 + wc * 32 + ni * 16 + lr;
        A[(size_t)row * KC + col] = (f16)acc[mi][ni][r];
      }
}

// ---------------- Kernel 2: out = A @ B, B generated on the fly ---------------------
// B[2(f-1)+0][t] = cos(2pi f t / V), B[2(f-1)+1][t] = -sin(2pi f t / V), f=1..256.
// 128x128 tile, BK=64, A via global_load_lds (source-side swizzle), B via rotation
// recurrence in regs (2 chains of 16 freqs per t-column) -> swizzled ds_write_b128.
__global__ __launch_bounds__(256) void k2_synth(
    const f16* __restrict__ A, float* __restrict__ out) {
  __shared__ __align__(16) f16 As[128 * 64];
  __shared__ __align__(16) f16 Bs[128 * 64];
  const int tid = threadIdx.x;
  const int bn0 = blockIdx.x * 128;
  const int bm0 = blockIdx.y * 128;
  const int lane = tid & 63, wid = tid >> 6;
  const int lr = lane & 15, lg = lane >> 4;
  const int wr = wid >> 1, wc = wid & 1;

  // B generator: thread owns column nloc, chain g (freqs 16g+1.. within each K-step)
  const int nloc = tid & 127;
  const int g = tid >> 7;
  const int t = bn0 + nloc;
  const float w0 = TWO_PI / (float)V_N;
  float cr, ci, r1c, r1s, r17c, r17s;
  {
    int a1 = (int)(((long long)(16 * g + 1) * t) % V_N);  // exact reduction
    int a2 = (int)((long long)t % V_N);
    int a3 = (int)(((long long)17 * t) % V_N);
    __sincosf((float)a1 * w0, &ci, &cr);
    __sincosf((float)a2 * w0, &r1s, &r1c);
    __sincosf((float)a3 * w0, &r17s, &r17c);
  }

  f32x4 acc[4][4];
#pragma unroll
  for (int i = 0; i < 4; ++i)
#pragma unroll
    for (int j = 0; j < 4; ++j) acc[i][j] = (f32x4){0.f, 0.f, 0.f, 0.f};

  for (int s = 0; s < KC / 64; ++s) {
    // generate 16 (cos,-sin) pairs for this K-step: 15x rot1 + 1x rot17 (jump)
    f16x8 bch[4];
#pragma unroll
    for (int u = 0; u < 4; ++u)
#pragma unroll
      for (int p = 0; p < 4; ++p) {
        bch[u][2 * p]     = (f16)cr;
        bch[u][2 * p + 1] = (f16)(-ci);
        float rc = (u == 3 && p == 3) ? r17c : r1c;
        float rs = (u == 3 && p == 3) ? r17s : r1s;
        float nc = cr * rc - ci * rs;
        float ns = cr * rs + ci * rc;
        cr = nc; ci = ns;
      }
    __syncthreads();
    // stage A: 16 x global_load_lds_dwordx4 (4 per wave), source pre-swizzled
#pragma unroll
    for (int ii = 0; ii < 4; ++ii) {
      int i = wid * 4 + ii;
      int q = i * 64 + lane;
      int m = q >> 3, cl = q & 7;
      int cg = cl ^ (m & 7);
      gload_lds16(A + (size_t)(bm0 + m) * KC + s * 64 + cg * 8, &As[i * 512]);
    }
    // stage B: write generated chunks (swizzled)
#pragma unroll
    for (int u = 0; u < 4; ++u) {
      int c = 4 * g + u;
      *(f16x8*)&Bs[nloc * 64 + ((c ^ (nloc & 7)) << 3)] = bch[u];
    }
    __syncthreads();
#pragma unroll
    for (int kk = 0; kk < 2; ++kk) {
      const int cb = kk * 4 + lg;
      f16x8 a[4], b[4];
#pragma unroll
      for (int mi = 0; mi < 4; ++mi) {
        int row = wr * 64 + mi * 16 + lr;
        a[mi] = *(const f16x8*)&As[row * 64 + ((cb ^ (row & 7)) << 3)];
      }
#pragma unroll
      for (int ni = 0; ni < 4; ++ni) {
        int col = wc * 64 + ni * 16 + lr;
        b[ni] = *(const f16x8*)&Bs[col * 64 + ((cb ^ (col & 7)) << 3)];
      }
#pragma unroll
      for (int mi = 0; mi < 4; ++mi)
#pragma unroll
        for (int ni = 0; ni < 4; ++ni)
          acc[mi][ni] = __builtin_amdgcn_mfma_f32_16x16x32_f16(a[mi], b[ni], acc[mi][ni], 0, 0, 0);
    }
  }
  const float scale = 2.0f / (float)V_N;
#pragma unroll
  for (int ni = 0; ni < 4; ++ni) {
    int col = bn0 + wc * 64 + ni * 16 + lr;
    if (col < V_N) {
#pragma unroll
      for (int mi = 0; mi < 4; ++mi)
#pragma unroll
        for (int r = 0; r < 4; ++r) {
          int row = bm0 + wr * 64 + mi * 16 + lg * 4 + r;
          out[(size_t)row * V_N + col] = acc[mi][ni][r] * scale;
        }
    }
  }
}

extern "C" void kernel_launch(void* const* d_in, const int* in_sizes, int n_in,
                              void* d_out, int out_size, void* d_ws, size_t ws_size,
                              hipStream_t stream) {
  const float* h = (const float*)d_in[0];
  const float* w = (const float*)d_in[1];
  float* out = (float*)d_out;
  f16* A = (f16*)d_ws;  // MT*KC*2 = 4 MB scratch

  dim3 blk(256);
  dim3 g1(KC / 64, MT / 64);          // 8 x 64
  hipLaunchKernelGGL(k1_proj, g1, blk, 0, stream, h, w, A);
  dim3 g2((V_N + 127) / 128, MT / 128);  // 393 x 32
  hipLaunchKernelGGL(k2_synth, g2, blk, 0, stream, A, out);
}